// Round 1
// baseline (548.365 us; speedup 1.0000x reference)
//
#include <hip/hip_runtime.h>
#include <hip/hip_bf16.h>

#define B_ 32
#define S_ 2048
#define D_ 1024
#define BM 128
#define BN 128
#define BK 64
#define NK (D_ / BK)   // 16 K-steps

typedef __attribute__((ext_vector_type(8))) short bf16x8;
typedef __attribute__((ext_vector_type(4))) float f32x4;
typedef __attribute__((ext_vector_type(4))) float float4v;

// f32 -> bf16 round-to-nearest-even on raw bits
__device__ __forceinline__ short f2bf(float f) {
    union { float f; unsigned u; } uf;
    uf.f = f;
    unsigned u = uf.u;
    u += 0x7FFFu + ((u >> 16) & 1u);
    return (short)(u >> 16);
}

__global__ __launch_bounds__(256, 2) void fused_gemm(
    const float* __restrict__ midi,      // [B][S][D]
    const int*   __restrict__ scale_id,  // [B]
    const int*   __restrict__ mask,      // [B][S]
    const float* __restrict__ W,         // [3][D][D]  (out,in)
    const float* __restrict__ bias,      // [3][D]
    const float* __restrict__ scemb,     // [3][D]
    const float* __restrict__ bremb,     // [3][D]
    float*       __restrict__ out,       // high | mid | low, flat
    float*       __restrict__ ws)        // [B][D] masked-sum accumulators
{
    __shared__ __align__(16) short As[BM * BK];
    __shared__ __align__(16) short Bs[BM * BK];

    const int tid = threadIdx.x;

    // chunked XCD swizzle: hardware round-robins blockIdx across 8 XCDs;
    // remap so consecutive logical tiles (sharing an A-panel) share an XCD L2.
    const int NTI = D_ / BN;  // 8
    const int MTI = S_ / BM;  // 16
    const int NWG = B_ * MTI * NTI;  // 4096, divisible by 8
    const int CPX = NWG / 8;
    int lid = ((int)blockIdx.x % 8) * CPX + ((int)blockIdx.x / 8);
    int nt = lid % NTI;
    int mt = (lid / NTI) % MTI;
    int bb = lid / (NTI * MTI);

    const int sid = scale_id[bb];

    const float* aBase = midi + ((size_t)bb * S_ + (size_t)mt * BM) * D_;
    const float* bBase = W + ((size_t)sid * D_ + (size_t)nt * BN) * D_;

    // staging map: chunk c = tid + 256*i -> row = c>>3 (0..127), kpos = (c&7)*8
    const int r0 = tid >> 3;        // 0..31
    const int kp = (tid & 7) * 8;   // 0..56

    float4v aL[4], aH[4], bL[4], bH[4];

    auto load_regs = [&](int kt) {
        const int kc = kt * BK + kp;
#pragma unroll
        for (int i = 0; i < 4; ++i) {
            const float* pa = aBase + (size_t)(r0 + 32 * i) * D_ + kc;
            aL[i] = *(const float4v*)pa;
            aH[i] = *(const float4v*)(pa + 4);
            const float* pb = bBase + (size_t)(r0 + 32 * i) * D_ + kc;
            bL[i] = *(const float4v*)pb;
            bH[i] = *(const float4v*)(pb + 4);
        }
    };

    auto write_lds = [&]() {
#pragma unroll
        for (int i = 0; i < 4; ++i) {
            const int row = r0 + 32 * i;
            const int off = (row * BK + kp) ^ ((row & 7) << 3);  // halfword XOR swizzle
            bf16x8 va, vb;
#pragma unroll
            for (int j = 0; j < 4; ++j) {
                va[j]     = f2bf(aL[i][j]);
                va[4 + j] = f2bf(aH[i][j]);
                vb[j]     = f2bf(bL[i][j]);
                vb[4 + j] = f2bf(bH[i][j]);
            }
            *(bf16x8*)&As[off] = va;
            *(bf16x8*)&Bs[off] = vb;
        }
    };

    f32x4 acc[4][4];
#pragma unroll
    for (int mi = 0; mi < 4; ++mi)
#pragma unroll
        for (int ni = 0; ni < 4; ++ni)
            acc[mi][ni] = (f32x4){0.f, 0.f, 0.f, 0.f};

    const int lane = tid & 63;
    const int wid = tid >> 6;
    const int wm = wid >> 1, wn = wid & 1;   // 2x2 wave grid, each wave owns 64x64
    const int fr = lane & 15;                // A-row / B-col / C-col
    const int fg = lane >> 4;                // k-group / C-row group

    load_regs(0);
    write_lds();
    __syncthreads();

    for (int kt = 0; kt < NK; ++kt) {
        if (kt + 1 < NK) load_regs(kt + 1);  // issue next-tile HBM loads early
#pragma unroll
        for (int kk = 0; kk < 2; ++kk) {
            bf16x8 af[4], bfr[4];
#pragma unroll
            for (int mi = 0; mi < 4; ++mi) {
                const int row = wm * 64 + mi * 16 + fr;
                const int off = (row * BK + kk * 32 + fg * 8) ^ ((row & 7) << 3);
                af[mi] = *(const bf16x8*)&As[off];
            }
#pragma unroll
            for (int ni = 0; ni < 4; ++ni) {
                const int row = wn * 64 + ni * 16 + fr;
                const int off = (row * BK + kk * 32 + fg * 8) ^ ((row & 7) << 3);
                bfr[ni] = *(const bf16x8*)&Bs[off];
            }
#pragma unroll
            for (int mi = 0; mi < 4; ++mi)
#pragma unroll
                for (int ni = 0; ni < 4; ++ni)
                    acc[mi][ni] = __builtin_amdgcn_mfma_f32_16x16x32_bf16(
                        af[mi], bfr[ni], acc[mi][ni], 0, 0, 0);
        }
        __syncthreads();
        if (kt + 1 < NK) write_lds();
        __syncthreads();
    }

    // ---- epilogue: silu + embeds, write high/mid, masked column sums ----
    const int ncolbase = nt * BN + wn * 64;
    float bv[4], sv[4], b0v[4], b1v[4];
#pragma unroll
    for (int ni = 0; ni < 4; ++ni) {
        const int n = ncolbase + ni * 16 + fr;
        bv[ni]  = bias[sid * D_ + n];
        sv[ni]  = scemb[sid * D_ + n];
        b0v[ni] = bremb[0 * D_ + n];
        b1v[ni] = bremb[1 * D_ + n];
    }

    const size_t MIDOFF = (size_t)B_ * S_ * D_;
    float colsum[4] = {0.f, 0.f, 0.f, 0.f};

#pragma unroll
    for (int mi = 0; mi < 4; ++mi) {
        const int mrow0 = mt * BM + wm * 64 + mi * 16 + fg * 4;
        float mk[4];
#pragma unroll
        for (int r = 0; r < 4; ++r)
            mk[r] = (mask[(size_t)bb * S_ + mrow0 + r] > 0) ? 1.f : 0.f;
#pragma unroll
        for (int ni = 0; ni < 4; ++ni) {
            const int n = ncolbase + ni * 16 + fr;
#pragma unroll
            for (int r = 0; r < 4; ++r) {
                const float v = acc[mi][ni][r] + bv[ni];
                const float o = v / (1.f + __expf(-v)) + sv[ni];  // silu + scale_embed
                const size_t idx = ((size_t)bb * S_ + (size_t)(mrow0 + r)) * D_ + n;
                __builtin_nontemporal_store(o + b0v[ni], &out[idx]);
                __builtin_nontemporal_store(o + b1v[ni], &out[MIDOFF + idx]);
                colsum[ni] += mk[r] * o;
            }
        }
    }

#pragma unroll
    for (int ni = 0; ni < 4; ++ni) {
        float s = colsum[ni];
        s += __shfl_xor(s, 16);
        s += __shfl_xor(s, 32);
        if (fg == 0)
            atomicAdd(&ws[(size_t)bb * D_ + (ncolbase + ni * 16 + fr)], s);
    }
}

__global__ void finalize(const int* __restrict__ mask,
                         const float* __restrict__ ws,
                         const float* __restrict__ bremb,
                         float* __restrict__ out)
{
    const int b = blockIdx.x;
    const int tid = threadIdx.x;

    int c = 0;
    for (int s = tid; s < S_; s += 256)
        c += (mask[(size_t)b * S_ + s] > 0) ? 1 : 0;
#pragma unroll
    for (int m = 1; m < 64; m <<= 1)
        c += __shfl_xor(c, m);

    __shared__ int part[4];
    if ((tid & 63) == 0) part[tid >> 6] = c;
    __syncthreads();
    const float denom = fmaxf((float)(part[0] + part[1] + part[2] + part[3]), 1e-6f);
    const float inv = 1.f / denom;

    const size_t LOWOFF = (size_t)2 * B_ * S_ * D_;
    for (int e = tid; e < D_; e += 256)
        out[LOWOFF + (size_t)b * D_ + e] = ws[(size_t)b * D_ + e] * inv + bremb[2 * D_ + e];
}

extern "C" void kernel_launch(void* const* d_in, const int* in_sizes, int n_in,
                              void* d_out, int out_size, void* d_ws, size_t ws_size,
                              hipStream_t stream) {
    const float* midi     = (const float*)d_in[0];
    const int*   scale_id = (const int*)d_in[1];
    const int*   mask     = (const int*)d_in[2];
    const float* W        = (const float*)d_in[3];
    const float* bias     = (const float*)d_in[4];
    const float* scemb    = (const float*)d_in[5];
    const float* bremb    = (const float*)d_in[6];
    float* out = (float*)d_out;
    float* ws  = (float*)d_ws;

    hipMemsetAsync(ws, 0, (size_t)B_ * D_ * sizeof(float), stream);

    fused_gemm<<<dim3(B_ * (S_ / BM) * (D_ / BN)), dim3(256), 0, stream>>>(
        midi, scale_id, mask, W, bias, scemb, bremb, out, ws);

    finalize<<<dim3(B_), dim3(256), 0, stream>>>(mask, ws, bremb, out);
}

// Round 2
// 441.054 us; speedup vs baseline: 1.2433x; 1.2433x over previous
//
#include <hip/hip_runtime.h>
#include <hip/hip_bf16.h>

#define B_ 32
#define S_ 2048
#define D_ 1024
#define BM 128
#define BN 128
#define BK 64
#define NK (D_ / BK)   // 16 K-steps

typedef __attribute__((ext_vector_type(8))) short bf16x8;
typedef __attribute__((ext_vector_type(4))) float f32x4;
typedef __attribute__((ext_vector_type(4))) float float4v;

#define AS1 __attribute__((address_space(1)))
#define AS3 __attribute__((address_space(3)))

// f32 -> bf16 round-to-nearest-even on raw bits
__device__ __forceinline__ short f2bf(float f) {
    union { float f; unsigned u; } uf;
    uf.f = f;
    unsigned u = uf.u;
    u += 0x7FFFu + ((u >> 16) & 1u);
    return (short)(u >> 16);
}

// ---------------- pre-convert: f32 -> bf16, 8 floats/thread ----------------
__global__ __launch_bounds__(256) void cvt_bf16(const float4v* __restrict__ src,
                                                bf16x8* __restrict__ dst, int n8) {
    const int stride = gridDim.x * blockDim.x;
    for (int i = blockIdx.x * blockDim.x + threadIdx.x; i < n8; i += stride) {
        float4v a = src[2 * i], b = src[2 * i + 1];
        bf16x8 v;
#pragma unroll
        for (int j = 0; j < 4; ++j) {
            v[j]     = f2bf(a[j]);
            v[4 + j] = f2bf(b[j]);
        }
        dst[i] = v;
    }
}

// ---------------- fast path: bf16 operands, global_load_lds, dbuf ----------
__global__ __launch_bounds__(256, 2) void fused_gemm_bf16(
    const __hip_bfloat16* __restrict__ aBf,   // [B][S][D] bf16
    const __hip_bfloat16* __restrict__ wBf,   // [3][D][D] bf16
    const int*   __restrict__ scale_id,
    const int*   __restrict__ mask,
    const float* __restrict__ bias,
    const float* __restrict__ scemb,
    const float* __restrict__ bremb,
    float*       __restrict__ out,
    float*       __restrict__ colws)
{
    __shared__ __align__(16) short As[2][BM * BK];
    __shared__ __align__(16) short Bs[2][BM * BK];

    const int tid = threadIdx.x;
    const int lane = tid & 63;
    const int wid = tid >> 6;

    // chunked XCD swizzle (NWG=4096 divisible by 8)
    const int NTI = D_ / BN;  // 8
    const int MTI = S_ / BM;  // 16
    const int NWG = B_ * MTI * NTI;
    const int CPX = NWG / 8;
    int lid = ((int)blockIdx.x % 8) * CPX + ((int)blockIdx.x / 8);
    int nt = lid % NTI;
    int mt = (lid / NTI) % MTI;
    int bb = lid / (NTI * MTI);

    const int sid = scale_id[bb];

    const __hip_bfloat16* aBase = aBf + ((size_t)bb * S_ + (size_t)mt * BM) * D_;
    const __hip_bfloat16* bBase = wBf + ((size_t)sid * D_ + (size_t)nt * BN) * D_;

    // stage: lane l of segment seg writes LDS bytes seg*1024 + l*16
    //   -> row = seg*8 + (l>>3), col-byte cb = (l&7)*16 within the 128B row-Ktile.
    // Both-sides swizzle: source col-byte = cb ^ ((row&7)<<4); read applies same XOR.
    const int l3 = lane >> 3;
    const int cb = (lane & 7) * 16;

    auto stage = [&](int buf, int kt) {
#pragma unroll
        for (int c = 0; c < 4; ++c) {
            const int seg = c * 4 + wid;
            const int row = seg * 8 + l3;
            const int scb = cb ^ ((row & 7) << 4);
            const __hip_bfloat16* ga = aBase + (size_t)row * D_ + kt * BK + (scb >> 1);
            const __hip_bfloat16* gb = bBase + (size_t)row * D_ + kt * BK + (scb >> 1);
            __builtin_amdgcn_global_load_lds((const AS1 unsigned int*)ga,
                (AS3 unsigned int*)&As[buf][seg * 512], 16, 0, 0);
            __builtin_amdgcn_global_load_lds((const AS1 unsigned int*)gb,
                (AS3 unsigned int*)&Bs[buf][seg * 512], 16, 0, 0);
        }
    };

    f32x4 acc[4][4];
#pragma unroll
    for (int mi = 0; mi < 4; ++mi)
#pragma unroll
        for (int ni = 0; ni < 4; ++ni)
            acc[mi][ni] = (f32x4){0.f, 0.f, 0.f, 0.f};

    const int wm = wid >> 1, wn = wid & 1;   // 2x2 wave grid, 64x64 per wave
    const int fr = lane & 15;
    const int fg = lane >> 4;

    stage(0, 0);
    asm volatile("s_waitcnt vmcnt(0)" ::: "memory");
    __syncthreads();

    int buf = 0;
    for (int kt = 0; kt < NK; ++kt) {
        if (kt + 1 < NK) stage(buf ^ 1, kt + 1);
#pragma unroll
        for (int kk = 0; kk < 2; ++kk) {
            bf16x8 af[4], bfr[4];
#pragma unroll
            for (int mi = 0; mi < 4; ++mi) {
                const int row = wm * 64 + mi * 16 + fr;
                const int byt = row * 128 + ((kk * 64 + fg * 16) ^ ((fr & 7) << 4));
                af[mi] = *(const bf16x8*)((const char*)&As[buf][0] + byt);
            }
#pragma unroll
            for (int ni = 0; ni < 4; ++ni) {
                const int row = wn * 64 + ni * 16 + fr;
                const int byt = row * 128 + ((kk * 64 + fg * 16) ^ ((fr & 7) << 4));
                bfr[ni] = *(const bf16x8*)((const char*)&Bs[buf][0] + byt);
            }
#pragma unroll
            for (int mi = 0; mi < 4; ++mi)
#pragma unroll
                for (int ni = 0; ni < 4; ++ni)
                    acc[mi][ni] = __builtin_amdgcn_mfma_f32_16x16x32_bf16(
                        af[mi], bfr[ni], acc[mi][ni], 0, 0, 0);
        }
        asm volatile("s_waitcnt vmcnt(0)" ::: "memory");
        __syncthreads();
        buf ^= 1;
    }

    // ---- epilogue: silu + embeds, write high/mid, masked column sums ----
    const int ncolbase = nt * BN + wn * 64;
    float bv[4], sv[4], b0v[4], b1v[4];
#pragma unroll
    for (int ni = 0; ni < 4; ++ni) {
        const int n = ncolbase + ni * 16 + fr;
        bv[ni]  = bias[sid * D_ + n];
        sv[ni]  = scemb[sid * D_ + n];
        b0v[ni] = bremb[0 * D_ + n];
        b1v[ni] = bremb[1 * D_ + n];
    }

    const size_t MIDOFF = (size_t)B_ * S_ * D_;
    float colsum[4] = {0.f, 0.f, 0.f, 0.f};

#pragma unroll
    for (int mi = 0; mi < 4; ++mi) {
        const int mrow0 = mt * BM + wm * 64 + mi * 16 + fg * 4;
        float mk[4];
#pragma unroll
        for (int r = 0; r < 4; ++r)
            mk[r] = (mask[(size_t)bb * S_ + mrow0 + r] > 0) ? 1.f : 0.f;
#pragma unroll
        for (int ni = 0; ni < 4; ++ni) {
            const int n = ncolbase + ni * 16 + fr;
#pragma unroll
            for (int r = 0; r < 4; ++r) {
                const float v = acc[mi][ni][r] + bv[ni];
                const float o = v / (1.f + __expf(-v)) + sv[ni];  // silu + scale_embed
                const size_t idx = ((size_t)bb * S_ + (size_t)(mrow0 + r)) * D_ + n;
                __builtin_nontemporal_store(o + b0v[ni], &out[idx]);
                __builtin_nontemporal_store(o + b1v[ni], &out[MIDOFF + idx]);
                colsum[ni] += mk[r] * o;
            }
        }
    }

#pragma unroll
    for (int ni = 0; ni < 4; ++ni) {
        float s = colsum[ni];
        s += __shfl_xor(s, 16);
        s += __shfl_xor(s, 32);
        if (fg == 0)
            atomicAdd(&colws[(size_t)bb * D_ + (ncolbase + ni * 16 + fr)], s);
    }
}

// ---------------- fallback path (round-1 kernel, f32 reg-staging) ----------
__global__ __launch_bounds__(256, 2) void fused_gemm_f32(
    const float* __restrict__ midi,
    const int*   __restrict__ scale_id,
    const int*   __restrict__ mask,
    const float* __restrict__ W,
    const float* __restrict__ bias,
    const float* __restrict__ scemb,
    const float* __restrict__ bremb,
    float*       __restrict__ out,
    float*       __restrict__ ws)
{
    __shared__ __align__(16) short As[BM * BK];
    __shared__ __align__(16) short Bs[BM * BK];

    const int tid = threadIdx.x;
    const int NTI = D_ / BN;
    const int MTI = S_ / BM;
    const int NWG = B_ * MTI * NTI;
    const int CPX = NWG / 8;
    int lid = ((int)blockIdx.x % 8) * CPX + ((int)blockIdx.x / 8);
    int nt = lid % NTI;
    int mt = (lid / NTI) % MTI;
    int bb = lid / (NTI * MTI);

    const int sid = scale_id[bb];
    const float* aBase = midi + ((size_t)bb * S_ + (size_t)mt * BM) * D_;
    const float* bBase = W + ((size_t)sid * D_ + (size_t)nt * BN) * D_;

    const int r0 = tid >> 3;
    const int kp = (tid & 7) * 8;

    float4v aL[4], aH[4], bL[4], bH[4];

    auto load_regs = [&](int kt) {
        const int kc = kt * BK + kp;
#pragma unroll
        for (int i = 0; i < 4; ++i) {
            const float* pa = aBase + (size_t)(r0 + 32 * i) * D_ + kc;
            aL[i] = *(const float4v*)pa;
            aH[i] = *(const float4v*)(pa + 4);
            const float* pb = bBase + (size_t)(r0 + 32 * i) * D_ + kc;
            bL[i] = *(const float4v*)pb;
            bH[i] = *(const float4v*)(pb + 4);
        }
    };

    auto write_lds = [&]() {
#pragma unroll
        for (int i = 0; i < 4; ++i) {
            const int row = r0 + 32 * i;
            const int off = (row * BK + kp) ^ ((row & 7) << 3);
            bf16x8 va, vb;
#pragma unroll
            for (int j = 0; j < 4; ++j) {
                va[j]     = f2bf(aL[i][j]);
                va[4 + j] = f2bf(aH[i][j]);
                vb[j]     = f2bf(bL[i][j]);
                vb[4 + j] = f2bf(bH[i][j]);
            }
            *(bf16x8*)&As[off] = va;
            *(bf16x8*)&Bs[off] = vb;
        }
    };

    f32x4 acc[4][4];
#pragma unroll
    for (int mi = 0; mi < 4; ++mi)
#pragma unroll
        for (int ni = 0; ni < 4; ++ni)
            acc[mi][ni] = (f32x4){0.f, 0.f, 0.f, 0.f};

    const int lane = tid & 63;
    const int wid = tid >> 6;
    const int wm = wid >> 1, wn = wid & 1;
    const int fr = lane & 15;
    const int fg = lane >> 4;

    load_regs(0);
    write_lds();
    __syncthreads();

    for (int kt = 0; kt < NK; ++kt) {
        if (kt + 1 < NK) load_regs(kt + 1);
#pragma unroll
        for (int kk = 0; kk < 2; ++kk) {
            bf16x8 af[4], bfr[4];
#pragma unroll
            for (int mi = 0; mi < 4; ++mi) {
                const int row = wm * 64 + mi * 16 + fr;
                const int off = (row * BK + kk * 32 + fg * 8) ^ ((row & 7) << 3);
                af[mi] = *(const bf16x8*)&As[off];
            }
#pragma unroll
            for (int ni = 0; ni < 4; ++ni) {
                const int row = wn * 64 + ni * 16 + fr;
                const int off = (row * BK + kk * 32 + fg * 8) ^ ((row & 7) << 3);
                bfr[ni] = *(const bf16x8*)&Bs[off];
            }
#pragma unroll
            for (int mi = 0; mi < 4; ++mi)
#pragma unroll
                for (int ni = 0; ni < 4; ++ni)
                    acc[mi][ni] = __builtin_amdgcn_mfma_f32_16x16x32_bf16(
                        af[mi], bfr[ni], acc[mi][ni], 0, 0, 0);
        }
        __syncthreads();
        if (kt + 1 < NK) write_lds();
        __syncthreads();
    }

    const int ncolbase = nt * BN + wn * 64;
    float bv[4], sv[4], b0v[4], b1v[4];
#pragma unroll
    for (int ni = 0; ni < 4; ++ni) {
        const int n = ncolbase + ni * 16 + fr;
        bv[ni]  = bias[sid * D_ + n];
        sv[ni]  = scemb[sid * D_ + n];
        b0v[ni] = bremb[0 * D_ + n];
        b1v[ni] = bremb[1 * D_ + n];
    }

    const size_t MIDOFF = (size_t)B_ * S_ * D_;
    float colsum[4] = {0.f, 0.f, 0.f, 0.f};

#pragma unroll
    for (int mi = 0; mi < 4; ++mi) {
        const int mrow0 = mt * BM + wm * 64 + mi * 16 + fg * 4;
        float mk[4];
#pragma unroll
        for (int r = 0; r < 4; ++r)
            mk[r] = (mask[(size_t)bb * S_ + mrow0 + r] > 0) ? 1.f : 0.f;
#pragma unroll
        for (int ni = 0; ni < 4; ++ni) {
            const int n = ncolbase + ni * 16 + fr;
#pragma unroll
            for (int r = 0; r < 4; ++r) {
                const float v = acc[mi][ni][r] + bv[ni];
                const float o = v / (1.f + __expf(-v)) + sv[ni];
                const size_t idx = ((size_t)bb * S_ + (size_t)(mrow0 + r)) * D_ + n;
                __builtin_nontemporal_store(o + b0v[ni], &out[idx]);
                __builtin_nontemporal_store(o + b1v[ni], &out[MIDOFF + idx]);
                colsum[ni] += mk[r] * o;
            }
        }
    }

#pragma unroll
    for (int ni = 0; ni < 4; ++ni) {
        float s = colsum[ni];
        s += __shfl_xor(s, 16);
        s += __shfl_xor(s, 32);
        if (fg == 0)
            atomicAdd(&ws[(size_t)bb * D_ + (ncolbase + ni * 16 + fr)], s);
    }
}

__global__ void finalize(const int* __restrict__ mask,
                         const float* __restrict__ ws,
                         const float* __restrict__ bremb,
                         float* __restrict__ out)
{
    const int b = blockIdx.x;
    const int tid = threadIdx.x;

    int c = 0;
    for (int s = tid; s < S_; s += 256)
        c += (mask[(size_t)b * S_ + s] > 0) ? 1 : 0;
#pragma unroll
    for (int m = 1; m < 64; m <<= 1)
        c += __shfl_xor(c, m);

    __shared__ int part[4];
    if ((tid & 63) == 0) part[tid >> 6] = c;
    __syncthreads();
    const float denom = fmaxf((float)(part[0] + part[1] + part[2] + part[3]), 1e-6f);
    const float inv = 1.f / denom;

    const size_t LOWOFF = (size_t)2 * B_ * S_ * D_;
    for (int e = tid; e < D_; e += 256)
        out[LOWOFF + (size_t)b * D_ + e] = ws[(size_t)b * D_ + e] * inv + bremb[2 * D_ + e];
}

extern "C" void kernel_launch(void* const* d_in, const int* in_sizes, int n_in,
                              void* d_out, int out_size, void* d_ws, size_t ws_size,
                              hipStream_t stream) {
    const float* midi     = (const float*)d_in[0];
    const int*   scale_id = (const int*)d_in[1];
    const int*   mask     = (const int*)d_in[2];
    const float* W        = (const float*)d_in[3];
    const float* bias     = (const float*)d_in[4];
    const float* scemb    = (const float*)d_in[5];
    const float* bremb    = (const float*)d_in[6];
    float* out = (float*)d_out;
    float* colws = (float*)d_ws;

    const size_t COLWS_B = (size_t)B_ * D_ * sizeof(float);            // 128 KB
    const size_t WBF_B   = (size_t)3 * D_ * D_ * sizeof(short);        // 6 MB
    const size_t ABF_B   = (size_t)B_ * S_ * D_ * sizeof(short);       // 128 MB
    const size_t need    = COLWS_B + WBF_B + ABF_B;

    hipMemsetAsync(colws, 0, COLWS_B, stream);

    if (ws_size >= need) {
        __hip_bfloat16* wBf = (__hip_bfloat16*)((char*)d_ws + COLWS_B);
        __hip_bfloat16* aBf = (__hip_bfloat16*)((char*)d_ws + COLWS_B + WBF_B);
        cvt_bf16<<<dim3(2048), dim3(256), 0, stream>>>(
            (const float4v*)midi, (bf16x8*)aBf, (B_ * S_ * D_) / 8);
        cvt_bf16<<<dim3(512), dim3(256), 0, stream>>>(
            (const float4v*)W, (bf16x8*)wBf, (3 * D_ * D_) / 8);
        fused_gemm_bf16<<<dim3(B_ * (S_ / BM) * (D_ / BN)), dim3(256), 0, stream>>>(
            aBf, wBf, scale_id, mask, bias, scemb, bremb, out, colws);
    } else {
        fused_gemm_f32<<<dim3(B_ * (S_ / BM) * (D_ / BN)), dim3(256), 0, stream>>>(
            midi, scale_id, mask, W, bias, scemb, bremb, out, colws);
    }

    finalize<<<dim3(B_), dim3(256), 0, stream>>>(mask, colws, bremb, out);
}

// Round 3
// 382.478 us; speedup vs baseline: 1.4337x; 1.1531x over previous
//
#include <hip/hip_runtime.h>
#include <hip/hip_bf16.h>

#define B_ 32
#define S_ 2048
#define D_ 1024
#define BM 128
#define BN 128
#define BK 64
#define NK (D_ / BK)   // 16 K-steps

typedef __attribute__((ext_vector_type(8))) short bf16x8;
typedef __attribute__((ext_vector_type(4))) float f32x4;
typedef __attribute__((ext_vector_type(4))) float float4v;

#define AS1 __attribute__((address_space(1)))
#define AS3 __attribute__((address_space(3)))

// f32 -> bf16 round-to-nearest-even on raw bits
__device__ __forceinline__ short f2bf(float f) {
    union { float f; unsigned u; } uf;
    uf.f = f;
    unsigned u = uf.u;
    u += 0x7FFFu + ((u >> 16) & 1u);
    return (short)(u >> 16);
}

// ---------------- pre-convert: f32 -> bf16, 8 floats/thread ----------------
__global__ __launch_bounds__(256) void cvt_bf16(const float4v* __restrict__ src,
                                                bf16x8* __restrict__ dst, int n8) {
    const int stride = gridDim.x * blockDim.x;
    for (int i = blockIdx.x * blockDim.x + threadIdx.x; i < n8; i += stride) {
        float4v a = src[2 * i], b = src[2 * i + 1];
        bf16x8 v;
#pragma unroll
        for (int j = 0; j < 4; ++j) {
            v[j]     = f2bf(a[j]);
            v[4 + j] = f2bf(b[j]);
        }
        dst[i] = v;
    }
}

// ---------------- fast path: bf16 operands, global_load_lds, dbuf ----------
__global__ __launch_bounds__(256, 2) void fused_gemm_bf16(
    const __hip_bfloat16* __restrict__ aBf,   // [B][S][D] bf16
    const __hip_bfloat16* __restrict__ wBf,   // [3][D][D] bf16
    const int*   __restrict__ scale_id,
    const int*   __restrict__ mask,
    const float* __restrict__ bias,
    const float* __restrict__ scemb,
    const float* __restrict__ bremb,
    float*       __restrict__ out,
    float*       __restrict__ colws)
{
    __shared__ __align__(16) short As[2][BM * BK];
    __shared__ __align__(16) short Bs[2][BM * BK];

    const int tid = threadIdx.x;
    const int lane = tid & 63;
    const int wid = tid >> 6;

    // chunked XCD swizzle (NWG=4096 divisible by 8)
    const int NTI = D_ / BN;  // 8
    const int MTI = S_ / BM;  // 16
    const int NWG = B_ * MTI * NTI;
    const int CPX = NWG / 8;
    int lid = ((int)blockIdx.x % 8) * CPX + ((int)blockIdx.x / 8);
    int nt = lid % NTI;
    int mt = (lid / NTI) % MTI;
    int bb = lid / (NTI * MTI);

    const int sid = scale_id[bb];

    const __hip_bfloat16* aBase = aBf + ((size_t)bb * S_ + (size_t)mt * BM) * D_;
    const __hip_bfloat16* bBase = wBf + ((size_t)sid * D_ + (size_t)nt * BN) * D_;

    // stage: lane l of segment seg writes LDS bytes seg*1024 + l*16
    //   -> row = seg*8 + (l>>3), col-byte cb = (l&7)*16 within the 128B row-Ktile.
    // Both-sides swizzle: source col-byte = cb ^ ((row&7)<<4); read applies same XOR.
    const int l3 = lane >> 3;
    const int cb = (lane & 7) * 16;

    auto stage = [&](int buf, int kt) {
#pragma unroll
        for (int c = 0; c < 4; ++c) {
            const int seg = c * 4 + wid;
            const int row = seg * 8 + l3;
            const int scb = cb ^ ((row & 7) << 4);
            const __hip_bfloat16* ga = aBase + (size_t)row * D_ + kt * BK + (scb >> 1);
            const __hip_bfloat16* gb = bBase + (size_t)row * D_ + kt * BK + (scb >> 1);
            __builtin_amdgcn_global_load_lds((const AS1 unsigned int*)ga,
                (AS3 unsigned int*)&As[buf][seg * 512], 16, 0, 0);
            __builtin_amdgcn_global_load_lds((const AS1 unsigned int*)gb,
                (AS3 unsigned int*)&Bs[buf][seg * 512], 16, 0, 0);
        }
    };

    f32x4 acc[4][4];
#pragma unroll
    for (int mi = 0; mi < 4; ++mi)
#pragma unroll
        for (int ni = 0; ni < 4; ++ni)
            acc[mi][ni] = (f32x4){0.f, 0.f, 0.f, 0.f};

    const int wm = wid >> 1, wn = wid & 1;   // 2x2 wave grid, 64x64 per wave
    const int fr = lane & 15;
    const int fg = lane >> 4;

    stage(0, 0);
    asm volatile("s_waitcnt vmcnt(0)" ::: "memory");
    __syncthreads();

    int buf = 0;
    for (int kt = 0; kt < NK; ++kt) {
        if (kt + 1 < NK) stage(buf ^ 1, kt + 1);
#pragma unroll
        for (int kk = 0; kk < 2; ++kk) {
            bf16x8 af[4], bfr[4];
#pragma unroll
            for (int mi = 0; mi < 4; ++mi) {
                const int row = wm * 64 + mi * 16 + fr;
                const int byt = row * 128 + ((kk * 64 + fg * 16) ^ ((fr & 7) << 4));
                af[mi] = *(const bf16x8*)((const char*)&As[buf][0] + byt);
            }
#pragma unroll
            for (int ni = 0; ni < 4; ++ni) {
                const int row = wn * 64 + ni * 16 + fr;
                const int byt = row * 128 + ((kk * 64 + fg * 16) ^ ((fr & 7) << 4));
                bfr[ni] = *(const bf16x8*)((const char*)&Bs[buf][0] + byt);
            }
#pragma unroll
            for (int mi = 0; mi < 4; ++mi)
#pragma unroll
                for (int ni = 0; ni < 4; ++ni)
                    acc[mi][ni] = __builtin_amdgcn_mfma_f32_16x16x32_bf16(
                        af[mi], bfr[ni], acc[mi][ni], 0, 0, 0);
        }
        asm volatile("s_waitcnt vmcnt(0)" ::: "memory");
        __syncthreads();
        buf ^= 1;
    }

    // ---- epilogue phase 1: silu + scale_embed in-register, masked colsums ----
    const int ncolbase = nt * BN + wn * 64;
    float bv[4], sv[4];
#pragma unroll
    for (int ni = 0; ni < 4; ++ni) {
        const int n = ncolbase + ni * 16 + fr;
        bv[ni] = bias[sid * D_ + n];
        sv[ni] = scemb[sid * D_ + n];
    }

    float colsum[4] = {0.f, 0.f, 0.f, 0.f};
#pragma unroll
    for (int mi = 0; mi < 4; ++mi) {
        const int mrow0 = mt * BM + wm * 64 + mi * 16 + fg * 4;
        float mk[4];
#pragma unroll
        for (int r = 0; r < 4; ++r)
            mk[r] = (mask[(size_t)bb * S_ + mrow0 + r] > 0) ? 1.f : 0.f;
#pragma unroll
        for (int ni = 0; ni < 4; ++ni) {
#pragma unroll
            for (int r = 0; r < 4; ++r) {
                const float v = acc[mi][ni][r] + bv[ni];
                const float o = v / (1.f + __expf(-v)) + sv[ni];  // silu + scale_embed
                acc[mi][ni][r] = o;
                colsum[ni] += mk[r] * o;
            }
        }
    }

#pragma unroll
    for (int ni = 0; ni < 4; ++ni) {
        float s = colsum[ni];
        s += __shfl_xor(s, 16);
        s += __shfl_xor(s, 32);
        if (fg == 0)
            atomicAdd(&colws[(size_t)bb * D_ + (ncolbase + ni * 16 + fr)], s);
    }

    // ---- epilogue phase 2: LDS bounce -> coalesced float4 stores ----
    // Reuse As (32 KB) as a padded [32][132] f32 tile (16.9 KB).
    float* ldsF = (float*)&As[0][0];
    const int lrowR = tid >> 3;   // 0..31 read row
    const int c8 = tid & 7;       // read col-quad base

    float4v b0q[4], b1q[4];
#pragma unroll
    for (int q = 0; q < 4; ++q) {
        const int gcol = nt * BN + (c8 + q * 8) * 4;
        b0q[q] = *(const float4v*)&bremb[0 * D_ + gcol];
        b1q[q] = *(const float4v*)&bremb[1 * D_ + gcol];
    }

    const size_t MIDOFF = (size_t)B_ * S_ * D_;

#pragma unroll
    for (int mi = 0; mi < 4; ++mi) {
        // write this mi's 16 values: rows (wm*16 + fg*4 + r), cols (wn*64 + ni*16 + fr)
#pragma unroll
        for (int ni = 0; ni < 4; ++ni)
#pragma unroll
            for (int r = 0; r < 4; ++r)
                ldsF[(wm * 16 + fg * 4 + r) * 132 + wn * 64 + ni * 16 + fr] =
                    acc[mi][ni][r];
        __syncthreads();

        const int grow = mt * BM + (lrowR >> 4) * 64 + mi * 16 + (lrowR & 15);
        const size_t rowbase = ((size_t)bb * S_ + grow) * D_ + nt * BN;
#pragma unroll
        for (int q = 0; q < 4; ++q) {
            const int c4 = c8 + q * 8;
            float4v v = *(const float4v*)&ldsF[lrowR * 132 + c4 * 4];
            float4v h = v + b0q[q];
            float4v m = v + b1q[q];
            __builtin_nontemporal_store(h, (float4v*)&out[rowbase + c4 * 4]);
            __builtin_nontemporal_store(m, (float4v*)&out[MIDOFF + rowbase + c4 * 4]);
        }
        __syncthreads();
    }
}

// ---------------- fallback path (f32 reg-staging, round-1 kernel) ----------
__global__ __launch_bounds__(256, 2) void fused_gemm_f32(
    const float* __restrict__ midi,
    const int*   __restrict__ scale_id,
    const int*   __restrict__ mask,
    const float* __restrict__ W,
    const float* __restrict__ bias,
    const float* __restrict__ scemb,
    const float* __restrict__ bremb,
    float*       __restrict__ out,
    float*       __restrict__ ws)
{
    __shared__ __align__(16) short As[BM * BK];
    __shared__ __align__(16) short Bs[BM * BK];

    const int tid = threadIdx.x;
    const int NTI = D_ / BN;
    const int MTI = S_ / BM;
    const int NWG = B_ * MTI * NTI;
    const int CPX = NWG / 8;
    int lid = ((int)blockIdx.x % 8) * CPX + ((int)blockIdx.x / 8);
    int nt = lid % NTI;
    int mt = (lid / NTI) % MTI;
    int bb = lid / (NTI * MTI);

    const int sid = scale_id[bb];
    const float* aBase = midi + ((size_t)bb * S_ + (size_t)mt * BM) * D_;
    const float* bBase = W + ((size_t)sid * D_ + (size_t)nt * BN) * D_;

    const int r0 = tid >> 3;
    const int kp = (tid & 7) * 8;

    float4v aL[4], aH[4], bL[4], bH[4];

    auto load_regs = [&](int kt) {
        const int kc = kt * BK + kp;
#pragma unroll
        for (int i = 0; i < 4; ++i) {
            const float* pa = aBase + (size_t)(r0 + 32 * i) * D_ + kc;
            aL[i] = *(const float4v*)pa;
            aH[i] = *(const float4v*)(pa + 4);
            const float* pb = bBase + (size_t)(r0 + 32 * i) * D_ + kc;
            bL[i] = *(const float4v*)pb;
            bH[i] = *(const float4v*)(pb + 4);
        }
    };

    auto write_lds = [&]() {
#pragma unroll
        for (int i = 0; i < 4; ++i) {
            const int row = r0 + 32 * i;
            const int off = (row * BK + kp) ^ ((row & 7) << 3);
            bf16x8 va, vb;
#pragma unroll
            for (int j = 0; j < 4; ++j) {
                va[j]     = f2bf(aL[i][j]);
                va[4 + j] = f2bf(aH[i][j]);
                vb[j]     = f2bf(bL[i][j]);
                vb[4 + j] = f2bf(bH[i][j]);
            }
            *(bf16x8*)&As[off] = va;
            *(bf16x8*)&Bs[off] = vb;
        }
    };

    f32x4 acc[4][4];
#pragma unroll
    for (int mi = 0; mi < 4; ++mi)
#pragma unroll
        for (int ni = 0; ni < 4; ++ni)
            acc[mi][ni] = (f32x4){0.f, 0.f, 0.f, 0.f};

    const int lane = tid & 63;
    const int wid = tid >> 6;
    const int wm = wid >> 1, wn = wid & 1;
    const int fr = lane & 15;
    const int fg = lane >> 4;

    load_regs(0);
    write_lds();
    __syncthreads();

    for (int kt = 0; kt < NK; ++kt) {
        if (kt + 1 < NK) load_regs(kt + 1);
#pragma unroll
        for (int kk = 0; kk < 2; ++kk) {
            bf16x8 af[4], bfr[4];
#pragma unroll
            for (int mi = 0; mi < 4; ++mi) {
                const int row = wm * 64 + mi * 16 + fr;
                const int off = (row * BK + kk * 32 + fg * 8) ^ ((row & 7) << 3);
                af[mi] = *(const bf16x8*)&As[off];
            }
#pragma unroll
            for (int ni = 0; ni < 4; ++ni) {
                const int row = wn * 64 + ni * 16 + fr;
                const int off = (row * BK + kk * 32 + fg * 8) ^ ((row & 7) << 3);
                bfr[ni] = *(const bf16x8*)&Bs[off];
            }
#pragma unroll
            for (int mi = 0; mi < 4; ++mi)
#pragma unroll
                for (int ni = 0; ni < 4; ++ni)
                    acc[mi][ni] = __builtin_amdgcn_mfma_f32_16x16x32_bf16(
                        af[mi], bfr[ni], acc[mi][ni], 0, 0, 0);
        }
        __syncthreads();
        if (kt + 1 < NK) write_lds();
        __syncthreads();
    }

    const int ncolbase = nt * BN + wn * 64;
    float bv[4], sv[4], b0v[4], b1v[4];
#pragma unroll
    for (int ni = 0; ni < 4; ++ni) {
        const int n = ncolbase + ni * 16 + fr;
        bv[ni]  = bias[sid * D_ + n];
        sv[ni]  = scemb[sid * D_ + n];
        b0v[ni] = bremb[0 * D_ + n];
        b1v[ni] = bremb[1 * D_ + n];
    }

    const size_t MIDOFF = (size_t)B_ * S_ * D_;
    float colsum[4] = {0.f, 0.f, 0.f, 0.f};

#pragma unroll
    for (int mi = 0; mi < 4; ++mi) {
        const int mrow0 = mt * BM + wm * 64 + mi * 16 + fg * 4;
        float mk[4];
#pragma unroll
        for (int r = 0; r < 4; ++r)
            mk[r] = (mask[(size_t)bb * S_ + mrow0 + r] > 0) ? 1.f : 0.f;
#pragma unroll
        for (int ni = 0; ni < 4; ++ni) {
            const int n = ncolbase + ni * 16 + fr;
#pragma unroll
            for (int r = 0; r < 4; ++r) {
                const float v = acc[mi][ni][r] + bv[ni];
                const float o = v / (1.f + __expf(-v)) + sv[ni];
                const size_t idx = ((size_t)bb * S_ + (size_t)(mrow0 + r)) * D_ + n;
                __builtin_nontemporal_store(o + b0v[ni], &out[idx]);
                __builtin_nontemporal_store(o + b1v[ni], &out[MIDOFF + idx]);
                colsum[ni] += mk[r] * o;
            }
        }
    }

#pragma unroll
    for (int ni = 0; ni < 4; ++ni) {
        float s = colsum[ni];
        s += __shfl_xor(s, 16);
        s += __shfl_xor(s, 32);
        if (fg == 0)
            atomicAdd(&ws[(size_t)bb * D_ + (ncolbase + ni * 16 + fr)], s);
    }
}

__global__ void finalize(const int* __restrict__ mask,
                         const float* __restrict__ ws,
                         const float* __restrict__ bremb,
                         float* __restrict__ out)
{
    const int b = blockIdx.x;
    const int tid = threadIdx.x;

    int c = 0;
    for (int s = tid; s < S_; s += 256)
        c += (mask[(size_t)b * S_ + s] > 0) ? 1 : 0;
#pragma unroll
    for (int m = 1; m < 64; m <<= 1)
        c += __shfl_xor(c, m);

    __shared__ int part[4];
    if ((tid & 63) == 0) part[tid >> 6] = c;
    __syncthreads();
    const float denom = fmaxf((float)(part[0] + part[1] + part[2] + part[3]), 1e-6f);
    const float inv = 1.f / denom;

    const size_t LOWOFF = (size_t)2 * B_ * S_ * D_;
    for (int e = tid; e < D_; e += 256)
        out[LOWOFF + (size_t)b * D_ + e] = ws[(size_t)b * D_ + e] * inv + bremb[2 * D_ + e];
}

extern "C" void kernel_launch(void* const* d_in, const int* in_sizes, int n_in,
                              void* d_out, int out_size, void* d_ws, size_t ws_size,
                              hipStream_t stream) {
    const float* midi     = (const float*)d_in[0];
    const int*   scale_id = (const int*)d_in[1];
    const int*   mask     = (const int*)d_in[2];
    const float* W        = (const float*)d_in[3];
    const float* bias     = (const float*)d_in[4];
    const float* scemb    = (const float*)d_in[5];
    const float* bremb    = (const float*)d_in[6];
    float* out = (float*)d_out;
    float* colws = (float*)d_ws;

    const size_t COLWS_B = (size_t)B_ * D_ * sizeof(float);            // 128 KB
    const size_t WBF_B   = (size_t)3 * D_ * D_ * sizeof(short);        // 6 MB
    const size_t ABF_B   = (size_t)B_ * S_ * D_ * sizeof(short);       // 128 MB
    const size_t need    = COLWS_B + WBF_B + ABF_B;

    hipMemsetAsync(colws, 0, COLWS_B, stream);

    if (ws_size >= need) {
        __hip_bfloat16* wBf = (__hip_bfloat16*)((char*)d_ws + COLWS_B);
        __hip_bfloat16* aBf = (__hip_bfloat16*)((char*)d_ws + COLWS_B + WBF_B);
        cvt_bf16<<<dim3(2048), dim3(256), 0, stream>>>(
            (const float4v*)midi, (bf16x8*)aBf, (B_ * S_ * D_) / 8);
        cvt_bf16<<<dim3(512), dim3(256), 0, stream>>>(
            (const float4v*)W, (bf16x8*)wBf, (3 * D_ * D_) / 8);
        fused_gemm_bf16<<<dim3(B_ * (S_ / BM) * (D_ / BN)), dim3(256), 0, stream>>>(
            aBf, wBf, scale_id, mask, bias, scemb, bremb, out, colws);
    } else {
        fused_gemm_f32<<<dim3(B_ * (S_ / BM) * (D_ / BN)), dim3(256), 0, stream>>>(
            midi, scale_id, mask, W, bias, scemb, bremb, out, colws);
    }

    finalize<<<dim3(B_), dim3(256), 0, stream>>>(mask, colws, bremb, out);
}